// Round 7
// baseline (1647.602 us; speedup 1.0000x reference)
//
#include <hip/hip_runtime.h>
#include <hip/hip_bf16.h>
#include <cstdint>
#include <cstddef>

// Problem dims (fixed by setup_inputs)
#define TDIM 2048
#define HDIM 4096
#define MDIM 14336

typedef __attribute__((ext_vector_type(8))) __bf16 bf16x8;
typedef __attribute__((ext_vector_type(4))) float f32x4;

#define VMW(n) asm volatile("s_waitcnt vmcnt(" #n ")" ::: "memory")
#define BARR                                  \
  do {                                        \
    asm volatile("" ::: "memory");            \
    __builtin_amdgcn_s_barrier();             \
    asm volatile("" ::: "memory");            \
  } while (0)

__device__ __constant__ float NF4_LUT[16] = {
    -1.0f, -0.6961928009986877f, -0.5250730514526367f, -0.39491748809814453f,
    -0.28444138169288635f, -0.18477343022823334f, -0.09105003625154495f, 0.0f,
    0.07958029955625534f, 0.16093020141124725f, 0.24611230194568634f,
    0.33791524171829224f, 0.44070982933044434f, 0.5626170039176941f,
    0.7229568362236023f, 1.0f};

__device__ __forceinline__ void g2l16(const void* g, void* l) {
  __builtin_amdgcn_global_load_lds(
      (const __attribute__((address_space(1))) unsigned int*)g,
      (__attribute__((address_space(3))) unsigned int*)l, 16, 0, 0);
}

// ------------------------------------------------------------ x f32 -> bf16
__global__ __launch_bounds__(256) void f32_to_bf16_k(
    const float* __restrict__ in, __hip_bfloat16* __restrict__ out, int n8) {
  for (int i = blockIdx.x * 256 + threadIdx.x; i < n8; i += gridDim.x * 256) {
    const float4* p = (const float4*)(in + (size_t)i * 8);
    float4 a = p[0], b = p[1];
    union { __hip_bfloat16 h[8]; int4 v; } u;
    u.h[0] = __float2bfloat16(a.x);
    u.h[1] = __float2bfloat16(a.y);
    u.h[2] = __float2bfloat16(a.z);
    u.h[3] = __float2bfloat16(a.w);
    u.h[4] = __float2bfloat16(b.x);
    u.h[5] = __float2bfloat16(b.y);
    u.h[6] = __float2bfloat16(b.z);
    u.h[7] = __float2bfloat16(b.w);
    *(int4*)(out + (size_t)i * 8) = u.v;
  }
}

// --------------------------------------------------- NF4 dequant -> bf16 W
__global__ __launch_bounds__(256) void dequant_nf4_k(
    const int* __restrict__ codes, const float* __restrict__ absmax,
    __hip_bfloat16* __restrict__ W, int K) {
  __shared__ float lut[16];
  if (threadIdx.x < 16) lut[threadIdx.x] = NF4_LUT[threadIdx.x];
  __syncthreads();
  const int row = blockIdx.x;
  const int K8 = K >> 3;
  const size_t rbase = (size_t)row * K;
  for (int c8 = threadIdx.x; c8 < K8; c8 += 256) {
    const int col = c8 << 3;
    const float am = absmax[(size_t)row * (K >> 6) + (col >> 6)];
    const int4* cp = (const int4*)(codes + rbase + col);
    int4 ca = cp[0], cb = cp[1];
    union { __hip_bfloat16 h[8]; int4 v; } u;
    u.h[0] = __float2bfloat16(lut[ca.x & 15] * am);
    u.h[1] = __float2bfloat16(lut[ca.y & 15] * am);
    u.h[2] = __float2bfloat16(lut[ca.z & 15] * am);
    u.h[3] = __float2bfloat16(lut[ca.w & 15] * am);
    u.h[4] = __float2bfloat16(lut[cb.x & 15] * am);
    u.h[5] = __float2bfloat16(lut[cb.y & 15] * am);
    u.h[6] = __float2bfloat16(lut[cb.z & 15] * am);
    u.h[7] = __float2bfloat16(lut[cb.w & 15] * am);
    *(int4*)(W + rbase + col) = u.v;
  }
}

// --------------------------------------- R1-exact 128x128 GEMM (safe legs)
// EPI: 0 = store bf16 (gate); 2 = store f32 (down)
template <int EPI>
__global__ __launch_bounds__(256, 2) void gemm_nt_k(
    const __hip_bfloat16* __restrict__ A, const __hip_bfloat16* __restrict__ B,
    void* __restrict__ Cv, const __hip_bfloat16* __restrict__ Gin,
    int M, int N, int K) {
  __shared__ __align__(16) char sA[128 * 128];
  __shared__ __align__(16) char sB[128 * 128];

  const int tid = threadIdx.x;
  const int lane = tid & 63;
  const int wid = tid >> 6;

  const int nbn = N >> 7;
  const int nwg = (M >> 7) * nbn;
  const int cpx = nwg >> 3;
  const int bid = blockIdx.x;
  const int wg = (bid & 7) * cpx + (bid >> 3);
  const int bm = wg / nbn, bn = wg % nbn;

  const int srow = lane >> 3;
  const int scolb = ((lane & 7) ^ srow) << 4;
  const char* gA = (const char*)A +
      ((size_t)(bm * 128 + wid * 8 + srow) * K) * 2 + scolb;
  const char* gB = (const char*)B +
      ((size_t)(bn * 128 + wid * 8 + srow) * K) * 2 + scolb;
  const size_t cstep = (size_t)64 * K;
  char* lA = sA + wid * 1024;
  char* lB = sB + wid * 1024;

  const int wm = wid >> 1, wn = wid & 1;
  const int colsw = (((lane >> 4) << 4) ^ ((lane & 7) << 4));
  const int aoff = (wm * 64 + (lane & 15)) * 128 + colsw;
  const int boff = (wn * 64 + (lane & 15)) * 128 + colsw;

  f32x4 acc[4][4] = {};

  const int nk = K >> 6;
  for (int kt = 0; kt < nk; ++kt) {
    const char* pa = gA + (size_t)kt * 128;
    const char* pb = gB + (size_t)kt * 128;
#pragma unroll
    for (int c = 0; c < 4; ++c) {
      g2l16(pa + c * cstep, lA + c * 4096);
      g2l16(pb + c * cstep, lB + c * 4096);
    }
    __syncthreads();
#pragma unroll
    for (int ks = 0; ks < 2; ++ks) {
      bf16x8 af[4], bfr[4];
#pragma unroll
      for (int i = 0; i < 4; ++i) {
        af[i] = *(const bf16x8*)(sA + ((aoff + i * 2048) ^ (ks << 6)));
        bfr[i] = *(const bf16x8*)(sB + ((boff + i * 2048) ^ (ks << 6)));
      }
#pragma unroll
      for (int mi = 0; mi < 4; ++mi)
#pragma unroll
        for (int nj = 0; nj < 4; ++nj)
          acc[mi][nj] = __builtin_amdgcn_mfma_f32_16x16x32_bf16(
              af[mi], bfr[nj], acc[mi][nj], 0, 0, 0);
    }
    __syncthreads();
  }

  const int row0 = bm * 128 + wm * 64 + ((lane >> 4) << 2);
  const int col0 = bn * 128 + wn * 64 + (lane & 15);
#pragma unroll
  for (int mi = 0; mi < 4; ++mi) {
#pragma unroll
    for (int nj = 0; nj < 4; ++nj) {
#pragma unroll
      for (int r = 0; r < 4; ++r) {
        const size_t idx =
            (size_t)(row0 + mi * 16 + r) * N + (col0 + nj * 16);
        const float v = acc[mi][nj][r];
        if (EPI == 0) {
          ((__hip_bfloat16*)Cv)[idx] = __float2bfloat16(v);
        } else {
          ((float*)Cv)[idx] = v;
        }
      }
    }
  }
}

// ------------------------------- EXPERIMENT: 8-phase 256² pipelined (up leg)
// Reads issued ONE PHASE AHEAD of their MFMA (latency hidden under barrier+
// MFMA of current phase). Zigzag quads (0,0),(0,1),(1,1),(1,0) with held
// fragments -> 24 ds_read_b128/K-tile/wave (minimal). Per-phase counted
// vmcnt BEFORE the barrier that precedes dependent ds_reads (cross-wave
// visibility). Ledger derived call-by-call; every read covered exactly,
// >=3-phase staging flight time. Stage map (t=2i):
//  p0:A(t+1,h1,b1) p1:B(t+1,h1,b1) p2:A(t+2,h0,b0) p3:B(t+2,h0,b0)
//  p4:A(t+2,h1,b0) p5:B(t+2,h1,b0) p6:A(t+3,h0,b1) p7:B(t+3,h0,b1)
// vmcnt checkpoints (phase start): p0:4, p3:6, p4:4, p7:6.
#define LDA8(dst, B_, H_)                                                     \
  _Pragma("unroll") for (int q = 0; q < 4; ++q) {                             \
    dst[q][0] = *(const bf16x8*)((uintptr_t)(aRd + (B_)*32768 +               \
                                             (H_)*16384 + q * 2048));         \
    dst[q][1] = *(const bf16x8*)(((uintptr_t)(aRd + (B_)*32768 +              \
                                              (H_)*16384 + q * 2048)) ^ 64);  \
  }
#define LDB4(dst, B_, H_)                                                     \
  _Pragma("unroll") for (int j = 0; j < 2; ++j) {                             \
    dst[j][0] = *(const bf16x8*)((uintptr_t)(bRd + (B_)*32768 +               \
                                             (H_)*16384 + j * 2048));         \
    dst[j][1] = *(const bf16x8*)(((uintptr_t)(bRd + (B_)*32768 +              \
                                              (H_)*16384 + j * 2048)) ^ 64);  \
  }
#define MFMA16(AF, BV, MH, NH)                                                \
  __builtin_amdgcn_s_setprio(1);                                              \
  _Pragma("unroll") for (int q = 0; q < 4; ++q)                               \
  _Pragma("unroll") for (int j = 0; j < 2; ++j) {                             \
    acc[(MH)*4 + q][(NH)*2 + j] = __builtin_amdgcn_mfma_f32_16x16x32_bf16(    \
        AF[q][0], BV[j][0], acc[(MH)*4 + q][(NH)*2 + j], 0, 0, 0);            \
    acc[(MH)*4 + q][(NH)*2 + j] = __builtin_amdgcn_mfma_f32_16x16x32_bf16(    \
        AF[q][1], BV[j][1], acc[(MH)*4 + q][(NH)*2 + j], 0, 0, 0);            \
  }                                                                           \
  __builtin_amdgcn_s_setprio(0)

__global__ __launch_bounds__(512, 1) void up_gemm8_k(
    const __hip_bfloat16* __restrict__ A, const __hip_bfloat16* __restrict__ B,
    __hip_bfloat16* __restrict__ Cv, const __hip_bfloat16* __restrict__ Gin,
    int M, int N, int K) {
  __shared__ __align__(16) char lds[131072];

  const int tid = threadIdx.x;
  const int lane = tid & 63;
  const int wid = tid >> 6;
  const int wm = wid >> 2, wn = wid & 3;

  const int nbn = N >> 8;
  const int nwg = (M >> 8) * nbn;
  const int q8 = nwg >> 3;
  const int bid = blockIdx.x;
  const int wg = (bid & 7) * q8 + (bid >> 3);
  const int bm = wg / nbn;
  const int bn = wg - bm * nbn;

  const size_t Kb = (size_t)K * 2;

  const int srow = lane >> 3;
  const int scw = ((lane & 7) ^ srow) << 4;
  const uint8_t* gA = (const uint8_t*)A +
      (size_t)(bm * 256 + wid * 8 + srow) * Kb + scw;
  const uint8_t* gB = (const uint8_t*)B +
      (size_t)(bn * 256 + wid * 8 + srow) * Kb + scw;
  char* ldsw = lds + wid * 1024;

  auto stageA = [&](int h, int b, int tt) {
    const uint8_t* g = gA + (size_t)(h * 128) * Kb + (size_t)tt * 128;
    char* l = ldsw + b * 32768 + h * 16384;
    g2l16(g, l);
    g2l16(g + 64 * Kb, l + 8192);
  };
  auto stageB = [&](int h, int b, int tt) {
    const uint8_t* g = gB + (size_t)(h * 128) * Kb + (size_t)tt * 128;
    char* l = ldsw + 65536 + b * 32768 + h * 16384;
    g2l16(g, l);
    g2l16(g + 64 * Kb, l + 8192);
  };

  const int colsw = (((lane >> 4) << 4) ^ ((lane & 7) << 4));
  const char* aRd = lds + (wm * 64 + (lane & 15)) * 128 + colsw;
  const char* bRd = lds + 65536 + (wn * 32 + (lane & 15)) * 128 + colsw;

  f32x4 acc[8][4] = {};
  bf16x8 afA[4][2], afB[4][2], bv0A[2][2], bv0B[2][2], bv1[2][2];

  const int nt = K >> 6;
  const int niter = nt >> 1;

  // prologue: virtual [i-1] stages p2..p7 (tile0 full -> b0, tile1 h0 -> b1)
  stageA(0, 0, 0); stageB(0, 0, 0); stageA(1, 0, 0); stageB(1, 0, 0);
  stageA(0, 1, 1); stageB(0, 1, 1);
  VMW(8);   // tile0-h0 (A,B) arrived
  BARR;
  LDA8(afA, 0, 0);   // pre-reads for P0 (tile0 quad(0,0))
  LDB4(bv0A, 0, 0);

  for (int i = 0; i < niter - 1; ++i) {
    const int t = i * 2;
    // P0
    VMW(4); BARR;
    LDB4(bv1, 0, 1);
    stageA(1, 1, t + 1);
    MFMA16(afA, bv0A, 0, 0);
    BARR;
    // P1
    BARR;
    LDA8(afB, 0, 1);
    stageB(1, 1, t + 1);
    MFMA16(afA, bv1, 0, 1);
    BARR;
    // P2
    BARR;
    stageA(0, 0, t + 2);
    MFMA16(afB, bv1, 1, 1);
    BARR;
    // P3
    VMW(6); BARR;
    LDA8(afA, 1, 0);
    LDB4(bv0B, 1, 0);
    stageB(0, 0, t + 2);
    MFMA16(afB, bv0A, 1, 0);
    BARR;
    // P4
    VMW(4); BARR;
    LDB4(bv1, 1, 1);
    stageA(1, 0, t + 2);
    MFMA16(afA, bv0B, 0, 0);
    BARR;
    // P5
    BARR;
    LDA8(afB, 1, 1);
    stageB(1, 0, t + 2);
    MFMA16(afA, bv1, 0, 1);
    BARR;
    // P6
    BARR;
    stageA(0, 1, t + 3);
    MFMA16(afB, bv1, 1, 1);
    BARR;
    // P7
    VMW(6); BARR;
    LDA8(afA, 0, 0);
    LDB4(bv0A, 0, 0);
    stageB(0, 1, t + 3);
    MFMA16(afB, bv0B, 1, 0);
    BARR;
  }
  {  // tail: tiles nt-2 (b0), nt-1 (b1); stage only nt-1 h1 at T0/T1
    // T0
    VMW(4); BARR;
    LDB4(bv1, 0, 1);
    stageA(1, 1, nt - 1);
    MFMA16(afA, bv0A, 0, 0);
    BARR;
    // T1
    BARR;
    LDA8(afB, 0, 1);
    stageB(1, 1, nt - 1);
    MFMA16(afA, bv1, 0, 1);
    BARR;
    // T2
    BARR;
    MFMA16(afB, bv1, 1, 1);
    BARR;
    // T3
    VMW(4); BARR;
    LDA8(afA, 1, 0);
    LDB4(bv0B, 1, 0);
    MFMA16(afB, bv0A, 1, 0);
    BARR;
    // T4
    VMW(0); BARR;
    LDB4(bv1, 1, 1);
    MFMA16(afA, bv0B, 0, 0);
    BARR;
    // T5
    BARR;
    LDA8(afB, 1, 1);
    MFMA16(afA, bv1, 0, 1);
    BARR;
    // T6
    BARR;
    MFMA16(afB, bv1, 1, 1);
    BARR;
    // T7
    BARR;
    MFMA16(afB, bv0B, 1, 0);
  }

  // epilogue: silu(G)*acc -> bf16 in place
#pragma unroll
  for (int mi = 0; mi < 8; ++mi) {
    const int grow0 = bm * 256 + (mi >> 2) * 128 + wm * 64 + (mi & 3) * 16 +
                      ((lane >> 4) << 2);
#pragma unroll
    for (int ni = 0; ni < 4; ++ni) {
      const int gcol = bn * 256 + (ni >> 1) * 128 + wn * 32 + (ni & 1) * 16 +
                       (lane & 15);
#pragma unroll
      for (int r = 0; r < 4; ++r) {
        const size_t idx = (size_t)(grow0 + r) * N + gcol;
        const float g = __bfloat162float(Gin[idx]);
        Cv[idx] = __float2bfloat16(g / (1.0f + __expf(-g)) * acc[mi][ni][r]);
      }
    }
  }
}

// ---------------------------------------------------------------- launcher
extern "C" void kernel_launch(void* const* d_in, const int* in_sizes, int n_in,
                              void* d_out, int out_size, void* d_ws,
                              size_t ws_size, hipStream_t stream) {
  const float* x = (const float*)d_in[0];
  const int* gate_codes = (const int*)d_in[1];
  const float* gate_absmax = (const float*)d_in[2];
  const int* up_codes = (const int*)d_in[3];
  const float* up_absmax = (const float*)d_in[4];
  const int* down_codes = (const int*)d_in[5];
  const float* down_absmax = (const float*)d_in[6];

  char* ws = (char*)d_ws;
  __hip_bfloat16* xb = (__hip_bfloat16*)ws;                              // 16 MB
  __hip_bfloat16* Wb = (__hip_bfloat16*)(ws + (size_t)TDIM * HDIM * 2);  // 112 MB
  __hip_bfloat16* Hb = (__hip_bfloat16*)(ws + (size_t)TDIM * HDIM * 2 +
                                         (size_t)MDIM * HDIM * 2);       // 56 MB

  f32_to_bf16_k<<<2048, 256, 0, stream>>>(x, xb, (TDIM * HDIM) / 8);

  // gate: R1-exact (safe)
  dequant_nf4_k<<<MDIM, 256, 0, stream>>>(gate_codes, gate_absmax, Wb, HDIM);
  gemm_nt_k<0><<<(TDIM / 128) * (MDIM / 128), 256, 0, stream>>>(
      xb, Wb, Hb, nullptr, TDIM, MDIM, HDIM);
  // up: EXPERIMENT 8-phase pipelined 256²
  dequant_nf4_k<<<MDIM, 256, 0, stream>>>(up_codes, up_absmax, Wb, HDIM);
  up_gemm8_k<<<(TDIM / 256) * (MDIM / 256), 512, 0, stream>>>(
      xb, Wb, Hb, Hb, TDIM, MDIM, HDIM);
  // down: R1-exact (safe), f32 store
  dequant_nf4_k<<<HDIM, 256, 0, stream>>>(down_codes, down_absmax, Wb, MDIM);
  gemm_nt_k<2><<<(TDIM / 128) * (HDIM / 128), 256, 0, stream>>>(
      Hb, Wb, (float*)d_out, nullptr, TDIM, HDIM, MDIM);
}